// Round 12
// baseline (210.499 us; speedup 1.0000x reference)
//
#include <hip/hip_runtime.h>
#include <hip/hip_cooperative_groups.h>
#include <stdint.h>

namespace cg = cooperative_groups;

#define BB 8
#define NN 4096
#define MM 32
#define KK 72
#define DD 78
#define PAD 76            // LDS row stride (floats): 76*4=304 B, 16B-aligned

static constexpr float EPSF = 1e-12f;

__device__ inline bool getmask(const void* masks, int flag, int i) {
  if (flag) return ((const unsigned char*)masks)[i] != 0;
  return ((const int*)masks)[i] != 0;
}

// orderable key: min over (cost asc, m asc) == reference argmin-first semantics
__device__ inline unsigned long long packkey(float c, int m) {
  unsigned u = __float_as_uint(c);
  unsigned k = ((int)u < 0) ? ~u : (u ^ 0x80000000u);
  return ((unsigned long long)k << 32) | (unsigned)m;
}

// Fused cooperative kernel: 512 blocks x 256 threads.
// Phase A: pairwise sad + per-block maxima (8 b x 64 chunks of 64 n;
//          2m x 4n tile per thread — r11 k_pairs verbatim).
// Phase B: blocks 0..255 = one (b,m) each: maxima reduce + cost + top-4.
// Phase C: finalize 64 outputs per block.
__global__ __launch_bounds__(256) void k_fused(
    const float* __restrict__ preds, const float* __restrict__ tgts,
    const int* __restrict__ imgw_p, const void* __restrict__ masks,
    float* __restrict__ sadA, float4* __restrict__ pc4, float* __restrict__ cls,
    float* __restrict__ part, unsigned* __restrict__ mmask,
    unsigned long long* __restrict__ cmin, int* __restrict__ flag,
    int* __restrict__ out) {
  cg::grid_group grid = cg::this_grid();

  __shared__ __align__(16) float t_xs[MM][PAD];
  __shared__ __align__(16) float px_s[64][PAD];
  __shared__ float pc_s[64][4];                   // cx, cy, th
  __shared__ float t_cx[MM], t_cy[MM], t_th[MM], t_len[MM];
  __shared__ float redv[4][3];
  // phase-B scratch
  __shared__ float bcast[3];
  __shared__ float scal[8];   // 0:cx 1:cy 2:th 3:len 4:v30
  __shared__ float ls_c[16];  __shared__ int ls_ci[16];
  __shared__ float ls_v[16];  __shared__ int ls_vi[16];

  const int b = blockIdx.x >> 6;
  const int n0 = (blockIdx.x & 63) << 6;          // 64 n per block
  const int tid = threadIdx.x;
  const float imgw = (float)(*imgw_p);
  const unsigned char* masks_raw = (const unsigned char*)masks;

  // ================= PHASE A =================
  // zero this block's mmask/cmin slice (512 blocks x 64 = B*N)
  if (tid < 64) {
    mmask[blockIdx.x * 64 + tid] = 0u;
    cmin[blockIdx.x * 64 + tid] = ~0ull;
  }
  // mask dtype detect: int32 masks have zero bytes at i%4!=0
  if (blockIdx.x == 0 && tid < 64) {
    int i = tid * 4;
    bool nz = false;
#pragma unroll
    for (int j = 1; j < 4; ++j)
      if (masks_raw[i + j] != 0) nz = true;
    unsigned long long bal = __ballot(nz);
    if (tid == 0) *flag = (bal != 0ull) ? 1 : 0;
  }

  // stage targets
  for (int idx = tid; idx < MM * DD; idx += 256) {
    int m = idx / DD, j = idx - m * DD;
    float v = tgts[((size_t)b * MM + m) * DD + j];
    if (j >= 6) t_xs[m][j - 6] = v;
    else if (j == 2) t_cx[m] = v;
    else if (j == 3) t_cy[m] = v;
    else if (j == 4) t_th[m] = v;
  }
  // stage the 64 pred x-rows
  for (int idx = tid; idx < 64 * KK; idx += 256) {
    int ni = idx / KK, k = idx - ni * KK;
    px_s[ni][k] = preds[((size_t)b * NN + (n0 + ni)) * DD + 6 + k];
  }
  // stage pred cx,cy,th
  if (tid < 192) {
    int ni = tid / 3, c = tid - ni * 3;
    pc_s[ni][c] = preds[((size_t)b * NN + (n0 + ni)) * DD + 2 + c];
  }
  // focal-cost class diffs (64 rows x 2 labels)
  if (tid < 128) {
    int ni = tid >> 1, c = tid & 1;
    float lg = preds[((size_t)b * NN + (n0 + ni)) * DD + c];
    float pp = 1.0f / (1.0f + expf(-lg));
    float neg = -logf(1.0f - pp + EPSF) * 0.75f * (pp * pp);
    float pos = -logf(pp + EPSF) * 0.25f * ((1.0f - pp) * (1.0f - pp));
    cls[((size_t)b * NN + (n0 + ni)) * 2 + c] = pos - neg;
  }
  __syncthreads();
  // export compact (cx,cy,th) table for phase B
  if (tid < 64)
    pc4[(size_t)b * NN + n0 + tid] =
        make_float4(pc_s[tid][0], pc_s[tid][1], pc_s[tid][2], 0.0f);
  // valid-count per target row (same predicate as the inner mask; exact <=72)
  if (tid < MM) {
    int V = 0;
    for (int k = 0; k < KK; ++k) {
      float t = t_xs[tid][k];
      if (t >= 0.0f && t < imgw) V++;
    }
    t_len[tid] = (float)(V > 0 ? V : 1);
  }
  __syncthreads();

  {
    const int mt = tid >> 4;       // 0..15 -> m = 2mt, 2mt+1
    const int nt = tid & 15;       // 0..15 -> n = n0 + nt + 16j, j=0..3
    const int mbase = mt << 1;

    const float4* t0r = reinterpret_cast<const float4*>(&t_xs[mbase + 0][0]);
    const float4* t1r = reinterpret_cast<const float4*>(&t_xs[mbase + 1][0]);
    const float4* p0r = reinterpret_cast<const float4*>(&px_s[nt][0]);
    const float4* p1r = reinterpret_cast<const float4*>(&px_s[nt + 16][0]);
    const float4* p2r = reinterpret_cast<const float4*>(&px_s[nt + 32][0]);
    const float4* p3r = reinterpret_cast<const float4*>(&px_s[nt + 48][0]);

    float s00 = 0.f, s01 = 0.f, s02 = 0.f, s03 = 0.f;
    float s10 = 0.f, s11 = 0.f, s12 = 0.f, s13 = 0.f;

#define MSK(T) \
  make_float4(((T).x >= 0.0f && (T).x < imgw) ? 1.0f : 0.0f, \
              ((T).y >= 0.0f && (T).y < imgw) ? 1.0f : 0.0f, \
              ((T).z >= 0.0f && (T).z < imgw) ? 1.0f : 0.0f, \
              ((T).w >= 0.0f && (T).w < imgw) ? 1.0f : 0.0f)
#define ST(S, T, A, P)                       \
  S = fmaf(fabsf((T).x - (P).x), (A).x, S);  \
  S = fmaf(fabsf((T).y - (P).y), (A).y, S);  \
  S = fmaf(fabsf((T).z - (P).z), (A).z, S);  \
  S = fmaf(fabsf((T).w - (P).w), (A).w, S);
#pragma unroll 6
    for (int q = 0; q < KK / 4; ++q) {
      float4 T0 = t0r[q], T1 = t1r[q];
      float4 A0 = MSK(T0), A1 = MSK(T1);    // mask from t only; reused over 4 n
      float4 P0 = p0r[q], P1 = p1r[q], P2 = p2r[q], P3 = p3r[q];
      ST(s00, T0, A0, P0) ST(s01, T0, A0, P1) ST(s02, T0, A0, P2) ST(s03, T0, A0, P3)
      ST(s10, T1, A1, P0) ST(s11, T1, A1, P1) ST(s12, T1, A1, P2) ST(s13, T1, A1, P3)
    }
#undef ST
#undef MSK

    float md = 0.f, mxy = 0.f, mth = 0.f;
#define FIN(S, MI, NJ)                                                        \
    {                                                                         \
      float sad = S;                                                          \
      int mi = mbase + (MI);                                                  \
      int nr = nt + 16 * (NJ);                                                \
      float dval = sad / t_len[mi];            /* IEEE div: == phase B */     \
      float dx = pc_s[nr][0] - t_cx[mi], dy = pc_s[nr][1] - t_cy[mi];         \
      float xyv = sqrtf(fmaf(dx, dx, dy * dy)); /* explicit fma: == B */      \
      float thv = fabsf(pc_s[nr][2] - t_th[mi]);                              \
      sadA[((size_t)(b * MM + mi)) * NN + n0 + nr] = sad;                     \
      md = fmaxf(md, dval); mxy = fmaxf(mxy, xyv); mth = fmaxf(mth, thv);     \
    }
    FIN(s00, 0, 0) FIN(s01, 0, 1) FIN(s02, 0, 2) FIN(s03, 0, 3)
    FIN(s10, 1, 0) FIN(s11, 1, 1) FIN(s12, 1, 2) FIN(s13, 1, 3)
#undef FIN

    // block max -> plain store to part[block][3] (NO atomics: round-5 lesson)
    for (int off = 32; off; off >>= 1) {
      md = fmaxf(md, __shfl_down(md, off));
      mxy = fmaxf(mxy, __shfl_down(mxy, off));
      mth = fmaxf(mth, __shfl_down(mth, off));
    }
    if ((tid & 63) == 0) {
      int w = tid >> 6;
      redv[w][0] = md; redv[w][1] = mxy; redv[w][2] = mth;
    }
    __syncthreads();
    if (tid == 0) {
      float a0 = fmaxf(fmaxf(redv[0][0], redv[1][0]), fmaxf(redv[2][0], redv[3][0]));
      float a1 = fmaxf(fmaxf(redv[0][1], redv[1][1]), fmaxf(redv[2][1], redv[3][1]));
      float a2 = fmaxf(fmaxf(redv[0][2], redv[1][2]), fmaxf(redv[2][2], redv[3][2]));
      part[(size_t)blockIdx.x * 3 + 0] = a0;
      part[(size_t)blockIdx.x * 3 + 1] = a1;
      part[(size_t)blockIdx.x * 3 + 2] = a2;
    }
  }

  __threadfence();
  grid.sync();

  // ================= PHASE B =================
  if (blockIdx.x < BB * MM) {
    const int b2 = blockIdx.x >> 5;
    const int m2 = blockIdx.x & 31;
    const bool act = getmask(masks, *flag, b2 * MM + m2);   // block-uniform
    if (act) {
      // reduce part[b2*64 .. +63][3] -> batch maxima (waves 0-2)
      if (tid < 192) {
        int g = tid >> 6, e = tid & 63;
        float v = part[((size_t)(b2 * 64 + e)) * 3 + g];
        for (int off = 32; off; off >>= 1) v = fmaxf(v, __shfl_down(v, off));
        if ((tid & 63) == 0) bcast[g] = v;
      }
      // wave 3: valid-count V + target scalars (same predicate as phase A)
      if (tid >= 192) {
        int lane = tid - 192;
        const float* trow = tgts + ((size_t)(b2 * MM + m2)) * DD;
        float t0 = trow[6 + lane];
        int c = (t0 >= 0.0f && t0 < imgw) ? 1 : 0;
        if (lane < KK - 64) {
          float t1 = trow[6 + 64 + lane];
          c += (t1 >= 0.0f && t1 < imgw) ? 1 : 0;
        }
        for (int off = 32; off; off >>= 1) c += __shfl_down(c, off);
        if (lane == 0) {
          float V = (float)c;
          scal[3] = (V > 0.f) ? V : 1.0f;
          scal[4] = 30.0f * V;
        }
        if (lane == 1) {
          scal[0] = trow[2]; scal[1] = trow[3]; scal[2] = trow[4];
        }
      }
      __syncthreads();

      const float maxd = fmaxf(bcast[0], 1e-6f);
      const float maxxy = fmaxf(bcast[1], 1e-6f);
      const float maxth = fmaxf(bcast[2], 1e-6f);
      const float tcx = scal[0], tcy = scal[1], tth = scal[2];
      const float len = scal[3], v30 = scal[4];
      const int label = (int)tgts[((size_t)b2 * MM + m2) * DD + 1];

      const int nb = tid << 4;     // 16 n per thread
      const float4* sadr = reinterpret_cast<const float4*>(
          sadA + ((size_t)(b2 * MM + m2)) * NN + nb);
      const float4* pcr = pc4 + (size_t)b2 * NN + nb;
      const float4* clr = reinterpret_cast<const float4*>(
          cls + ((size_t)b2 * NN + nb) * 2);

      float cc[16], vv[16];
#pragma unroll
      for (int g = 0; g < 4; ++g) {
        float4 s4 = sadr[g];
        float sa[4] = {s4.x, s4.y, s4.z, s4.w};
        float4 ca = clr[g * 2], cb = clr[g * 2 + 1];
        float clv[4] = {label ? ca.y : ca.x, label ? ca.w : ca.z,
                        label ? cb.y : cb.x, label ? cb.w : cb.z};
#pragma unroll
        for (int e = 0; e < 4; ++e) {
          float4 q = pcr[g * 4 + e];
          float sad = sa[e];
          float dval = sad / len;                    // == phase A bitwise
          float dx = q.x - tcx, dy = q.y - tcy;
          float xyv = sqrtf(fmaf(dx, dx, dy * dy));  // == phase A bitwise
          float thv = fabsf(q.z - tth);
          float iv = (v30 - sad) / ((v30 + sad) + 1e-9f);
          float ds = (1.0f - dval / maxd) + 0.01f;
          float xs = (1.0f - xyv / maxxy) + 0.01f;
          float ts = (1.0f - thv / maxth) + 0.01f;
          float r = (ds * xs) * ts;
          cc[g * 4 + e] = -(r * r) * 3.0f + clv[e] * 1.0f;
          vv[g * 4 + e] = fmaxf(iv, 0.0f);
        }
      }

      const int wid = tid >> 6, lane = tid & 63;
      unsigned usedC = 0, usedV = 0;
      float wcv[4]; int wci[4]; float wvv[4]; int wvi[4];

#pragma unroll
      for (int r = 0; r < 4; ++r) {
        // cost: wave min by (c asc, idx asc). Local: strict < keeps lowest
        // idx on ties since idx increases with e.
        float bv = 3e38f; int bi = 0x7fffffff; int be = -1;
#pragma unroll
        for (int e = 0; e < 16; ++e)
          if (!((usedC >> e) & 1) && cc[e] < bv) { bv = cc[e]; bi = nb + e; be = e; }
        float v = bv; int i = bi;
#pragma unroll
        for (int off = 32; off; off >>= 1) {
          float ov = __shfl_xor(v, off); int oi = __shfl_xor(i, off);
          if (ov < v || (ov == v && oi < i)) { v = ov; i = oi; }
        }
        if (be >= 0 && i == bi) usedC |= 1u << be;   // unique n -> unique winner
        wcv[r] = v; wci[r] = i;

        // iou: wave max by (v desc, idx asc)
        float bw = -1.0f; int bj = 0x7fffffff; int bf = -1;
#pragma unroll
        for (int e = 0; e < 16; ++e)
          if (!((usedV >> e) & 1) && vv[e] > bw) { bw = vv[e]; bj = nb + e; bf = e; }
        float w = bw; int j = bj;
#pragma unroll
        for (int off = 32; off; off >>= 1) {
          float ow = __shfl_xor(w, off); int oj = __shfl_xor(j, off);
          if (ow > w || (ow == w && oj < j)) { w = ow; j = oj; }
        }
        if (bf >= 0 && j == bj) usedV |= 1u << bf;
        wvv[r] = w; wvi[r] = j;
      }

      if (lane == 0) {
#pragma unroll
        for (int r = 0; r < 4; ++r) {
          ls_c[wid * 4 + r] = wcv[r]; ls_ci[wid * 4 + r] = wci[r];
          ls_v[wid * 4 + r] = wvv[r]; ls_vi[wid * 4 + r] = wvi[r];
        }
      }
      __syncthreads();

      if (tid < 64) {
        float c = (tid < 16) ? ls_c[tid] : 3e38f;
        int i = (tid < 16) ? ls_ci[tid] : 0x7fffffff;
        float w = (tid < 16) ? ls_v[tid] : -1.0f;
        int j = (tid < 16) ? ls_vi[tid] : 0x7fffffff;
        int gidx[4]; float gcst[4]; float gsum = 0.0f;
#pragma unroll
        for (int r = 0; r < 4; ++r) {
          float v = c; int vi = i;
#pragma unroll
          for (int off = 32; off; off >>= 1) {
            float ov = __shfl_xor(v, off); int oi = __shfl_xor(vi, off);
            if (ov < v || (ov == v && oi < vi)) { v = ov; vi = oi; }
          }
          if (i == vi) c = 3e38f;                    // consume winner
          gidx[r] = vi; gcst[r] = v;

          float u = w; int ui = j;
#pragma unroll
          for (int off = 32; off; off >>= 1) {
            float ou = __shfl_xor(u, off); int oi = __shfl_xor(ui, off);
            if (ou > u || (ou == u && oi < ui)) { u = ou; ui = oi; }
          }
          if (j == ui) w = -1.0f;
          gsum += u;
        }
        if (tid == 0) {
          int k = (int)gsum;                         // trunc == floor (gsum >= 0)
          if (k < 1) k = 1;
          if (k > 4) k = 4;
          for (int s = 0; s < k; ++s) {
            atomicOr(&mmask[(size_t)b2 * NN + gidx[s]], 1u << m2);
            atomicMin(&cmin[(size_t)b2 * NN + gidx[s]], packkey(gcst[s], m2));
          }
        }
      }
    }
  }

  __threadfence();
  grid.sync();

  // ================= PHASE C =================
  if (tid < 64) {
    int idx = blockIdx.x * 64 + tid;     // 512*64 = B*N
    unsigned mm = mmask[idx];
    int pc = __popc(mm);
    out[idx] = pc ? 1 : 0;
    out[BB * NN + idx] = pc ? (int)(unsigned)(cmin[idx] & 0xFFFFFFFFull) : -1;
  }
}

extern "C" void kernel_launch(void* const* d_in, const int* in_sizes, int n_in,
                              void* d_out, int out_size, void* d_ws, size_t ws_size,
                              hipStream_t stream) {
  const float* preds = (const float*)d_in[0];
  const float* tgts = (const float*)d_in[1];
  const void* masks = d_in[2];
  const int* imgw = (const int*)d_in[3];

  char* ws = (char*)d_ws;
  float* sadA = (float*)ws;                                   // B*M*N*4 = 4 MiB
  char* p = ws + (size_t)BB * MM * NN * sizeof(float);
  float4* pc4 = (float4*)p;                                   // B*N*16 = 512 KB
  p += (size_t)BB * NN * sizeof(float4);
  float* cls = (float*)p;                                     // B*N*2 floats
  p += (size_t)BB * NN * 2 * sizeof(float);
  float* part = (float*)p;                                    // 512*3 floats
  p += (size_t)1024 * 3 * sizeof(float);
  unsigned* mmask = (unsigned*)p;                             // B*N
  p += (size_t)BB * NN * sizeof(unsigned);
  unsigned long long* cmin = (unsigned long long*)p;          // B*N * 8B
  p += (size_t)BB * NN * sizeof(unsigned long long);
  int* flag = (int*)p;
  int* out = (int*)d_out;

  void* args[] = {&preds, &tgts, &imgw, &masks, &sadA, &pc4, &cls,
                  &part, &mmask, &cmin, &flag, &out};
  hipLaunchCooperativeKernel((void*)k_fused, dim3(BB * 64), dim3(256),
                             args, 0, stream);
}

// Round 13
// 61.651 us; speedup vs baseline: 3.4144x; 3.4144x over previous
//
#include <hip/hip_runtime.h>
#include <stdint.h>

#define BB 8
#define NN 4096
#define MM 32
#define KK 72
#define DD 78
#define PAD 76            // LDS row stride (floats): 76*4=304 B, 16B-aligned

static constexpr float EPSF = 1e-12f;

__device__ inline bool getmask(const void* masks, int flag, int i) {
  if (flag) return ((const unsigned char*)masks)[i] != 0;
  return ((const int*)masks)[i] != 0;
}

// orderable key: min over (cost asc, m asc) == reference argmin-first semantics
__device__ inline unsigned long long packkey(float c, int m) {
  unsigned u = __float_as_uint(c);
  unsigned k = ((int)u < 0) ? ~u : (u ^ 0x80000000u);
  return ((unsigned long long)k << 32) | (unsigned)m;
}

// ---------- pass A: 512 blocks = 8 b x 64 chunks(64 n); 256 thr = 16 mt x 16 nt
// each thread computes a 2m x 4n tile (8 pairs). Validity mask recomputed in
// VALU (depends only on t) -> no am_s in LDS: 6 b128 reads per q for 8 quads.
__global__ __launch_bounds__(256) void k_pairs(
    const float* __restrict__ preds, const float* __restrict__ tgts,
    const int* __restrict__ imgw_p, const unsigned char* __restrict__ masks_raw,
    float* __restrict__ sadA, float4* __restrict__ pc4, float* __restrict__ cls,
    float* __restrict__ part, unsigned* __restrict__ mmask,
    unsigned long long* __restrict__ cmin, int* __restrict__ flag,
    int* __restrict__ done) {
  __shared__ __align__(16) float t_xs[MM][PAD];
  __shared__ __align__(16) float px_s[64][PAD];
  __shared__ float pc_s[64][4];                   // cx, cy, th
  __shared__ float t_cx[MM], t_cy[MM], t_th[MM], t_len[MM];
  __shared__ float redv[4][3];

  const int b = blockIdx.x >> 6;
  const int n0 = (blockIdx.x & 63) << 6;          // 64 n per block
  const int tid = threadIdx.x;
  const float imgw = (float)(*imgw_p);

  // zero this block's mmask/cmin slice (512 blocks x 64 = B*N)
  if (tid < 64) {
    mmask[blockIdx.x * 64 + tid] = 0u;
    cmin[blockIdx.x * 64 + tid] = ~0ull;
  }
  // mask dtype detect: int32 masks have zero bytes at i%4!=0
  if (blockIdx.x == 0 && tid < 64) {
    int i = tid * 4;
    bool nz = false;
#pragma unroll
    for (int j = 1; j < 4; ++j)
      if (masks_raw[i + j] != 0) nz = true;
    unsigned long long bal = __ballot(nz);
    if (tid == 0) {
      *flag = (bal != 0ull) ? 1 : 0;
      *done = 0;                       // reset last-block counter every call
    }
  }

  // stage targets
  for (int idx = tid; idx < MM * DD; idx += 256) {
    int m = idx / DD, j = idx - m * DD;
    float v = tgts[((size_t)b * MM + m) * DD + j];
    if (j >= 6) t_xs[m][j - 6] = v;
    else if (j == 2) t_cx[m] = v;
    else if (j == 3) t_cy[m] = v;
    else if (j == 4) t_th[m] = v;
  }
  // stage the 64 pred x-rows
  for (int idx = tid; idx < 64 * KK; idx += 256) {
    int ni = idx / KK, k = idx - ni * KK;
    px_s[ni][k] = preds[((size_t)b * NN + (n0 + ni)) * DD + 6 + k];
  }
  // stage pred cx,cy,th
  if (tid < 192) {
    int ni = tid / 3, c = tid - ni * 3;
    pc_s[ni][c] = preds[((size_t)b * NN + (n0 + ni)) * DD + 2 + c];
  }
  // focal-cost class diffs (64 rows x 2 labels)
  if (tid < 128) {
    int ni = tid >> 1, c = tid & 1;
    float lg = preds[((size_t)b * NN + (n0 + ni)) * DD + c];
    float pp = 1.0f / (1.0f + expf(-lg));
    float neg = -logf(1.0f - pp + EPSF) * 0.75f * (pp * pp);
    float pos = -logf(pp + EPSF) * 0.25f * ((1.0f - pp) * (1.0f - pp));
    cls[((size_t)b * NN + (n0 + ni)) * 2 + c] = pos - neg;
  }
  __syncthreads();
  // export compact (cx,cy,th) table for k_assign
  if (tid < 64)
    pc4[(size_t)b * NN + n0 + tid] =
        make_float4(pc_s[tid][0], pc_s[tid][1], pc_s[tid][2], 0.0f);
  // valid-count per target row (same predicate as the inner mask; exact <=72)
  if (tid < MM) {
    int V = 0;
    for (int k = 0; k < KK; ++k) {
      float t = t_xs[tid][k];
      if (t >= 0.0f && t < imgw) V++;
    }
    t_len[tid] = (float)(V > 0 ? V : 1);
  }
  __syncthreads();

  const int mt = tid >> 4;       // 0..15 -> m = 2mt, 2mt+1
  const int nt = tid & 15;       // 0..15 -> n = n0 + nt + 16j, j=0..3
  const int mbase = mt << 1;

  const float4* t0r = reinterpret_cast<const float4*>(&t_xs[mbase + 0][0]);
  const float4* t1r = reinterpret_cast<const float4*>(&t_xs[mbase + 1][0]);
  const float4* p0r = reinterpret_cast<const float4*>(&px_s[nt][0]);
  const float4* p1r = reinterpret_cast<const float4*>(&px_s[nt + 16][0]);
  const float4* p2r = reinterpret_cast<const float4*>(&px_s[nt + 32][0]);
  const float4* p3r = reinterpret_cast<const float4*>(&px_s[nt + 48][0]);

  float s00 = 0.f, s01 = 0.f, s02 = 0.f, s03 = 0.f;
  float s10 = 0.f, s11 = 0.f, s12 = 0.f, s13 = 0.f;

#define MSK(T) \
  make_float4(((T).x >= 0.0f && (T).x < imgw) ? 1.0f : 0.0f, \
              ((T).y >= 0.0f && (T).y < imgw) ? 1.0f : 0.0f, \
              ((T).z >= 0.0f && (T).z < imgw) ? 1.0f : 0.0f, \
              ((T).w >= 0.0f && (T).w < imgw) ? 1.0f : 0.0f)
#define ST(S, T, A, P)                       \
  S = fmaf(fabsf((T).x - (P).x), (A).x, S);  \
  S = fmaf(fabsf((T).y - (P).y), (A).y, S);  \
  S = fmaf(fabsf((T).z - (P).z), (A).z, S);  \
  S = fmaf(fabsf((T).w - (P).w), (A).w, S);
#pragma unroll 6
  for (int q = 0; q < KK / 4; ++q) {
    float4 T0 = t0r[q], T1 = t1r[q];
    float4 A0 = MSK(T0), A1 = MSK(T1);      // mask from t only; reused over 4 n
    float4 P0 = p0r[q], P1 = p1r[q], P2 = p2r[q], P3 = p3r[q];
    ST(s00, T0, A0, P0) ST(s01, T0, A0, P1) ST(s02, T0, A0, P2) ST(s03, T0, A0, P3)
    ST(s10, T1, A1, P0) ST(s11, T1, A1, P1) ST(s12, T1, A1, P2) ST(s13, T1, A1, P3)
  }
#undef ST
#undef MSK

  float md = 0.f, mxy = 0.f, mth = 0.f;
#define FIN(S, MI, NJ)                                                        \
  {                                                                           \
    float sad = S;                                                            \
    int mi = mbase + (MI);                                                    \
    int nr = nt + 16 * (NJ);                                                  \
    float dval = sad / t_len[mi];            /* IEEE div: == k_assign */      \
    float dx = pc_s[nr][0] - t_cx[mi], dy = pc_s[nr][1] - t_cy[mi];           \
    float xyv = sqrtf(fmaf(dx, dx, dy * dy)); /* explicit fma: == k_assign */ \
    float thv = fabsf(pc_s[nr][2] - t_th[mi]);                                \
    sadA[((size_t)(b * MM + mi)) * NN + n0 + nr] = sad;                       \
    md = fmaxf(md, dval); mxy = fmaxf(mxy, xyv); mth = fmaxf(mth, thv);       \
  }
  FIN(s00, 0, 0) FIN(s01, 0, 1) FIN(s02, 0, 2) FIN(s03, 0, 3)
  FIN(s10, 1, 0) FIN(s11, 1, 1) FIN(s12, 1, 2) FIN(s13, 1, 3)
#undef FIN

  // block max -> plain store to part[block][3] (NO atomics: round-5 lesson)
  for (int off = 32; off; off >>= 1) {
    md = fmaxf(md, __shfl_down(md, off));
    mxy = fmaxf(mxy, __shfl_down(mxy, off));
    mth = fmaxf(mth, __shfl_down(mth, off));
  }
  if ((tid & 63) == 0) {
    int w = tid >> 6;
    redv[w][0] = md; redv[w][1] = mxy; redv[w][2] = mth;
  }
  __syncthreads();
  if (tid == 0) {
    float a0 = fmaxf(fmaxf(redv[0][0], redv[1][0]), fmaxf(redv[2][0], redv[3][0]));
    float a1 = fmaxf(fmaxf(redv[0][1], redv[1][1]), fmaxf(redv[2][1], redv[3][1]));
    float a2 = fmaxf(fmaxf(redv[0][2], redv[1][2]), fmaxf(redv[2][2], redv[3][2]));
    part[(size_t)blockIdx.x * 3 + 0] = a0;
    part[(size_t)blockIdx.x * 3 + 1] = a1;
    part[(size_t)blockIdx.x * 3 + 2] = a2;
  }
}

// ---------- pass C: maxima reduce + recompute metrics + cost + top-4 --------
// one block (1024 threads = 16 waves) per (b,m); thread t owns n = 4t..4t+3.
// Last block to finish (done-counter) also writes the outputs (merged k_final:
// no spin, no co-residency assumption -> no deadlock risk).
__global__ __launch_bounds__(1024) void k_assign(
    const float* __restrict__ sadA, const float4* __restrict__ pc4,
    const float* __restrict__ cls, const float* __restrict__ tgts,
    const int* __restrict__ imgw_p, const float* __restrict__ part,
    const void* __restrict__ masks, const int* __restrict__ flag,
    unsigned* __restrict__ mmask, unsigned long long* __restrict__ cmin,
    int* __restrict__ done, int* __restrict__ out) {
  const int b = blockIdx.x >> 5;
  const int m = blockIdx.x & 31;
  const bool act = getmask(masks, *flag, b * MM + m);   // block-uniform

  const int tid = threadIdx.x;
  __shared__ float bcast[3];
  __shared__ float scal[8];   // 0:cx 1:cy 2:th 3:len 4:v30
  __shared__ float ls_c[64];  __shared__ int ls_ci[64];
  __shared__ float ls_v[64];  __shared__ int ls_vi[64];
  __shared__ int lastflag;

  if (act) {
    // reduce part[b*64 .. +63][3] -> batch maxima (one wave per metric)
    if (tid < 192) {
      int g = tid >> 6, e = tid & 63;
      float v = part[((size_t)(b * 64 + e)) * 3 + g];
      for (int off = 32; off; off >>= 1) v = fmaxf(v, __shfl_down(v, off));
      if ((tid & 63) == 0) bcast[g] = v;
    }
    // wave 14: valid-count V for target row m (same predicate as k_pairs)
    if (tid >= 896 && tid < 960) {
      int lane = tid - 896;
      const float* trow = tgts + ((size_t)(b * MM + m)) * DD;
      const float imgw = (float)(*imgw_p);
      float t0 = trow[6 + lane];
      int c = (t0 >= 0.0f && t0 < imgw) ? 1 : 0;
      if (lane < KK - 64) {
        float t1 = trow[6 + 64 + lane];
        c += (t1 >= 0.0f && t1 < imgw) ? 1 : 0;
      }
      for (int off = 32; off; off >>= 1) c += __shfl_down(c, off);
      if (lane == 0) {
        float V = (float)c;
        scal[3] = (V > 0.f) ? V : 1.0f;
        scal[4] = 30.0f * V;
      }
    }
    if (tid == 1023) {
      const float* trow = tgts + ((size_t)(b * MM + m)) * DD;
      scal[0] = trow[2]; scal[1] = trow[3]; scal[2] = trow[4];
    }
    __syncthreads();

    const float maxd = fmaxf(bcast[0], 1e-6f);
    const float maxxy = fmaxf(bcast[1], 1e-6f);
    const float maxth = fmaxf(bcast[2], 1e-6f);
    const float tcx = scal[0], tcy = scal[1], tth = scal[2];
    const float len = scal[3], v30 = scal[4];
    const int label = (int)tgts[((size_t)b * MM + m) * DD + 1];

    const int n0 = tid << 2;
    float4 s4 = *reinterpret_cast<const float4*>(sadA + ((size_t)(b * MM + m)) * NN + n0);
    const float4* pcb = pc4 + (size_t)b * NN + n0;
    float4 q0 = pcb[0], q1 = pcb[1], q2 = pcb[2], q3 = pcb[3];
    const float4* cbase = reinterpret_cast<const float4*>(cls + ((size_t)b * NN + n0) * 2);
    float4 c0 = cbase[0], c1 = cbase[1];

    float se[4] = {s4.x, s4.y, s4.z, s4.w};
    float cxe[4] = {q0.x, q1.x, q2.x, q3.x};
    float cye[4] = {q0.y, q1.y, q2.y, q3.y};
    float the[4] = {q0.z, q1.z, q2.z, q3.z};
    float clv[4] = {label ? c0.y : c0.x, label ? c0.w : c0.z,
                    label ? c1.y : c1.x, label ? c1.w : c1.z};

    float cc[4]; int ci[4]; float vv[4];
#pragma unroll
    for (int e = 0; e < 4; ++e) {
      float sad = se[e];
      float dval = sad / len;                       // == k_pairs dval bitwise
      float dx = cxe[e] - tcx, dy = cye[e] - tcy;
      float xyv = sqrtf(fmaf(dx, dx, dy * dy));     // == k_pairs xyv bitwise
      float thv = fabsf(the[e] - tth);
      float iv = (v30 - sad) / ((v30 + sad) + 1e-9f);
      float ds = (1.0f - dval / maxd) + 0.01f;
      float xs = (1.0f - xyv / maxxy) + 0.01f;
      float ts = (1.0f - thv / maxth) + 0.01f;
      float r = (ds * xs) * ts;
      cc[e] = -(r * r) * 3.0f + clv[e] * 1.0f;
      ci[e] = n0 + e;
      vv[e] = fmaxf(iv, 0.0f);
    }

    const int wid = tid >> 6, lane = tid & 63;
    unsigned usedC = 0, usedV = 0;
    float wcv[4]; int wci[4]; float wvv[4]; int wvi[4];

#pragma unroll
    for (int r = 0; r < 4; ++r) {
      // ---- cost: extract wave min by (c asc, idx asc) ----
      float bv = 3e38f; int bi = 0x7fffffff; int be = -1;
#pragma unroll
      for (int e = 0; e < 4; ++e)
        if (!((usedC >> e) & 1) && (cc[e] < bv || (cc[e] == bv && ci[e] < bi))) {
          bv = cc[e]; bi = ci[e]; be = e;
        }
      float v = bv; int i = bi;
#pragma unroll
      for (int off = 32; off; off >>= 1) {
        float ov = __shfl_xor(v, off); int oi = __shfl_xor(i, off);
        if (ov < v || (ov == v && oi < i)) { v = ov; i = oi; }
      }
      if (be >= 0 && i == bi) usedC |= 1u << be;   // unique n -> unique winner
      wcv[r] = v; wci[r] = i;

      // ---- iou: extract wave max by (v desc, idx asc) ----
      float bw = -1.0f; int bj = 0x7fffffff; int bf = -1;
#pragma unroll
      for (int e = 0; e < 4; ++e)
        if (!((usedV >> e) & 1) && (vv[e] > bw || (vv[e] == bw && ci[e] < bj))) {
          bw = vv[e]; bj = ci[e]; bf = e;
        }
      float w = bw; int j = bj;
#pragma unroll
      for (int off = 32; off; off >>= 1) {
        float ow = __shfl_xor(w, off); int oj = __shfl_xor(j, off);
        if (ow > w || (ow == w && oj < j)) { w = ow; j = oj; }
      }
      if (bf >= 0 && j == bj) usedV |= 1u << bf;
      wvv[r] = w; wvi[r] = j;
    }

    if (lane == 0) {
#pragma unroll
      for (int r = 0; r < 4; ++r) {
        ls_c[wid * 4 + r] = wcv[r]; ls_ci[wid * 4 + r] = wci[r];
        ls_v[wid * 4 + r] = wvv[r]; ls_vi[wid * 4 + r] = wvi[r];
      }
    }
    __syncthreads();

    if (tid < 64) {
      float c = ls_c[tid]; int i = ls_ci[tid];
      float w = ls_v[tid]; int j = ls_vi[tid];
      int gidx[4]; float gcst[4]; float gsum = 0.0f;
#pragma unroll
      for (int r = 0; r < 4; ++r) {
        float v = c; int vi = i;
#pragma unroll
        for (int off = 32; off; off >>= 1) {
          float ov = __shfl_xor(v, off); int oi = __shfl_xor(vi, off);
          if (ov < v || (ov == v && oi < vi)) { v = ov; vi = oi; }
        }
        if (i == vi) c = 3e38f;                    // consume winner
        gidx[r] = vi; gcst[r] = v;

        float u = w; int ui = j;
#pragma unroll
        for (int off = 32; off; off >>= 1) {
          float ou = __shfl_xor(u, off); int oi = __shfl_xor(ui, off);
          if (ou > u || (ou == u && oi < ui)) { u = ou; ui = oi; }
        }
        if (j == ui) w = -1.0f;
        gsum += u;
      }
      if (tid == 0) {
        int k = (int)gsum;                         // trunc == floor (gsum >= 0)
        if (k < 1) k = 1;
        if (k > 4) k = 4;
        for (int s = 0; s < k; ++s) {
          atomicOr(&mmask[(size_t)b * NN + gidx[s]], 1u << m);
          atomicMin(&cmin[(size_t)b * NN + gidx[s]], packkey(gcst[s], m));
        }
      }
    }
  }

  // ---- last-block-done finalize (merged k_final; no spin) ----
  __syncthreads();
  if (tid == 0) {
    __threadfence();                     // release this block's atomics
    int prev = atomicAdd(done, 1);
    lastflag = (prev == BB * MM - 1) ? 1 : 0;
  }
  __syncthreads();
  if (lastflag) {
    __threadfence();                     // acquire all blocks' atomics
    for (int idx = tid; idx < BB * NN; idx += 1024) {
      unsigned mm = mmask[idx];
      int pc = __popc(mm);
      out[idx] = pc ? 1 : 0;
      out[BB * NN + idx] = pc ? (int)(unsigned)(cmin[idx] & 0xFFFFFFFFull) : -1;
    }
  }
}

extern "C" void kernel_launch(void* const* d_in, const int* in_sizes, int n_in,
                              void* d_out, int out_size, void* d_ws, size_t ws_size,
                              hipStream_t stream) {
  const float* preds = (const float*)d_in[0];
  const float* tgts = (const float*)d_in[1];
  const void* masks = d_in[2];
  const int* imgw = (const int*)d_in[3];

  char* ws = (char*)d_ws;
  float* sadA = (float*)ws;                                   // B*M*N*4 = 4 MiB
  char* p = ws + (size_t)BB * MM * NN * sizeof(float);
  float4* pc4 = (float4*)p;                                   // B*N*16 = 512 KB
  p += (size_t)BB * NN * sizeof(float4);
  float* cls = (float*)p;                                     // B*N*2 floats
  p += (size_t)BB * NN * 2 * sizeof(float);
  float* part = (float*)p;                                    // 512*3 floats
  p += (size_t)1024 * 3 * sizeof(float);
  unsigned* mmask = (unsigned*)p;                             // B*N
  p += (size_t)BB * NN * sizeof(unsigned);
  unsigned long long* cmin = (unsigned long long*)p;          // B*N * 8B
  p += (size_t)BB * NN * sizeof(unsigned long long);
  int* flag = (int*)p;
  int* done = (int*)(p + 64);

  k_pairs<<<dim3(BB * 64), dim3(256), 0, stream>>>(
      preds, tgts, imgw, (const unsigned char*)masks,
      sadA, pc4, cls, part, mmask, cmin, flag, done);
  k_assign<<<dim3(BB * MM), dim3(1024), 0, stream>>>(
      sadA, pc4, cls, tgts, imgw, part, masks, flag, mmask, cmin,
      done, (int*)d_out);
}

// Round 14
// 49.775 us; speedup vs baseline: 4.2290x; 1.2386x over previous
//
#include <hip/hip_runtime.h>
#include <stdint.h>

#define BB 8
#define NN 4096
#define MM 32
#define KK 72
#define DD 78
#define PAD 76            // LDS row stride (floats): 76*4=304 B, 16B-aligned

static constexpr float EPSF = 1e-12f;

__device__ inline bool getmask(const void* masks, int flag, int i) {
  if (flag) return ((const unsigned char*)masks)[i] != 0;
  return ((const int*)masks)[i] != 0;
}

// orderable key: min over (cost asc, m asc) == reference argmin-first semantics
__device__ inline unsigned long long packkey(float c, int m) {
  unsigned u = __float_as_uint(c);
  unsigned k = ((int)u < 0) ? ~u : (u ^ 0x80000000u);
  return ((unsigned long long)k << 32) | (unsigned)m;
}

// ---------- pass A: 512 blocks = 8 b x 64 chunks(64 n); 256 thr = 16 mt x 16 nt
// each thread computes a 2m x 4n tile (8 pairs). Validity mask recomputed in
// VALU (depends only on t) -> no am_s in LDS: 6 b128 reads per q for 8 quads.
__global__ __launch_bounds__(256) void k_pairs(
    const float* __restrict__ preds, const float* __restrict__ tgts,
    const int* __restrict__ imgw_p, const unsigned char* __restrict__ masks_raw,
    float* __restrict__ sadA, float4* __restrict__ pc4, float* __restrict__ cls,
    float* __restrict__ part, unsigned* __restrict__ mmask,
    unsigned long long* __restrict__ cmin, int* __restrict__ flag,
    int* __restrict__ done) {
  __shared__ __align__(16) float t_xs[MM][PAD];
  __shared__ __align__(16) float px_s[64][PAD];
  __shared__ float pc_s[64][4];                   // cx, cy, th
  __shared__ float t_cx[MM], t_cy[MM], t_th[MM], t_len[MM];
  __shared__ float redv[4][3];

  const int b = blockIdx.x >> 6;
  const int n0 = (blockIdx.x & 63) << 6;          // 64 n per block
  const int tid = threadIdx.x;
  const float imgw = (float)(*imgw_p);

  // zero this block's mmask/cmin slice (512 blocks x 64 = B*N)
  if (tid < 64) {
    mmask[blockIdx.x * 64 + tid] = 0u;
    cmin[blockIdx.x * 64 + tid] = ~0ull;
  }
  // reset per-batch done counters every call (graph replay safe)
  if (blockIdx.x == 0 && tid >= 64 && tid < 64 + BB) done[tid - 64] = 0;
  // mask dtype detect: int32 masks have zero bytes at i%4!=0
  if (blockIdx.x == 0 && tid < 64) {
    int i = tid * 4;
    bool nz = false;
#pragma unroll
    for (int j = 1; j < 4; ++j)
      if (masks_raw[i + j] != 0) nz = true;
    unsigned long long bal = __ballot(nz);
    if (tid == 0) *flag = (bal != 0ull) ? 1 : 0;
  }

  // stage targets
  for (int idx = tid; idx < MM * DD; idx += 256) {
    int m = idx / DD, j = idx - m * DD;
    float v = tgts[((size_t)b * MM + m) * DD + j];
    if (j >= 6) t_xs[m][j - 6] = v;
    else if (j == 2) t_cx[m] = v;
    else if (j == 3) t_cy[m] = v;
    else if (j == 4) t_th[m] = v;
  }
  // stage the 64 pred x-rows
  for (int idx = tid; idx < 64 * KK; idx += 256) {
    int ni = idx / KK, k = idx - ni * KK;
    px_s[ni][k] = preds[((size_t)b * NN + (n0 + ni)) * DD + 6 + k];
  }
  // stage pred cx,cy,th
  if (tid < 192) {
    int ni = tid / 3, c = tid - ni * 3;
    pc_s[ni][c] = preds[((size_t)b * NN + (n0 + ni)) * DD + 2 + c];
  }
  // focal-cost class diffs (64 rows x 2 labels)
  if (tid < 128) {
    int ni = tid >> 1, c = tid & 1;
    float lg = preds[((size_t)b * NN + (n0 + ni)) * DD + c];
    float pp = 1.0f / (1.0f + expf(-lg));
    float neg = -logf(1.0f - pp + EPSF) * 0.75f * (pp * pp);
    float pos = -logf(pp + EPSF) * 0.25f * ((1.0f - pp) * (1.0f - pp));
    cls[((size_t)b * NN + (n0 + ni)) * 2 + c] = pos - neg;
  }
  __syncthreads();
  // export compact (cx,cy,th) table for k_assign
  if (tid < 64)
    pc4[(size_t)b * NN + n0 + tid] =
        make_float4(pc_s[tid][0], pc_s[tid][1], pc_s[tid][2], 0.0f);
  // valid-count per target row (same predicate as the inner mask; exact <=72)
  if (tid < MM) {
    int V = 0;
    for (int k = 0; k < KK; ++k) {
      float t = t_xs[tid][k];
      if (t >= 0.0f && t < imgw) V++;
    }
    t_len[tid] = (float)(V > 0 ? V : 1);
  }
  __syncthreads();

  const int mt = tid >> 4;       // 0..15 -> m = 2mt, 2mt+1
  const int nt = tid & 15;       // 0..15 -> n = n0 + nt + 16j, j=0..3
  const int mbase = mt << 1;

  const float4* t0r = reinterpret_cast<const float4*>(&t_xs[mbase + 0][0]);
  const float4* t1r = reinterpret_cast<const float4*>(&t_xs[mbase + 1][0]);
  const float4* p0r = reinterpret_cast<const float4*>(&px_s[nt][0]);
  const float4* p1r = reinterpret_cast<const float4*>(&px_s[nt + 16][0]);
  const float4* p2r = reinterpret_cast<const float4*>(&px_s[nt + 32][0]);
  const float4* p3r = reinterpret_cast<const float4*>(&px_s[nt + 48][0]);

  float s00 = 0.f, s01 = 0.f, s02 = 0.f, s03 = 0.f;
  float s10 = 0.f, s11 = 0.f, s12 = 0.f, s13 = 0.f;

#define MSK(T) \
  make_float4(((T).x >= 0.0f && (T).x < imgw) ? 1.0f : 0.0f, \
              ((T).y >= 0.0f && (T).y < imgw) ? 1.0f : 0.0f, \
              ((T).z >= 0.0f && (T).z < imgw) ? 1.0f : 0.0f, \
              ((T).w >= 0.0f && (T).w < imgw) ? 1.0f : 0.0f)
#define ST(S, T, A, P)                       \
  S = fmaf(fabsf((T).x - (P).x), (A).x, S);  \
  S = fmaf(fabsf((T).y - (P).y), (A).y, S);  \
  S = fmaf(fabsf((T).z - (P).z), (A).z, S);  \
  S = fmaf(fabsf((T).w - (P).w), (A).w, S);
#pragma unroll 6
  for (int q = 0; q < KK / 4; ++q) {
    float4 T0 = t0r[q], T1 = t1r[q];
    float4 A0 = MSK(T0), A1 = MSK(T1);      // mask from t only; reused over 4 n
    float4 P0 = p0r[q], P1 = p1r[q], P2 = p2r[q], P3 = p3r[q];
    ST(s00, T0, A0, P0) ST(s01, T0, A0, P1) ST(s02, T0, A0, P2) ST(s03, T0, A0, P3)
    ST(s10, T1, A1, P0) ST(s11, T1, A1, P1) ST(s12, T1, A1, P2) ST(s13, T1, A1, P3)
  }
#undef ST
#undef MSK

  float md = 0.f, mxy = 0.f, mth = 0.f;
#define FIN(S, MI, NJ)                                                        \
  {                                                                           \
    float sad = S;                                                            \
    int mi = mbase + (MI);                                                    \
    int nr = nt + 16 * (NJ);                                                  \
    float dval = sad / t_len[mi];            /* IEEE div: == k_assign */      \
    float dx = pc_s[nr][0] - t_cx[mi], dy = pc_s[nr][1] - t_cy[mi];           \
    float xyv = sqrtf(fmaf(dx, dx, dy * dy)); /* explicit fma: == k_assign */ \
    float thv = fabsf(pc_s[nr][2] - t_th[mi]);                                \
    sadA[((size_t)(b * MM + mi)) * NN + n0 + nr] = sad;                       \
    md = fmaxf(md, dval); mxy = fmaxf(mxy, xyv); mth = fmaxf(mth, thv);       \
  }
  FIN(s00, 0, 0) FIN(s01, 0, 1) FIN(s02, 0, 2) FIN(s03, 0, 3)
  FIN(s10, 1, 0) FIN(s11, 1, 1) FIN(s12, 1, 2) FIN(s13, 1, 3)
#undef FIN

  // block max -> plain store to part[block][3] (NO atomics: round-5 lesson)
  for (int off = 32; off; off >>= 1) {
    md = fmaxf(md, __shfl_down(md, off));
    mxy = fmaxf(mxy, __shfl_down(mxy, off));
    mth = fmaxf(mth, __shfl_down(mth, off));
  }
  if ((tid & 63) == 0) {
    int w = tid >> 6;
    redv[w][0] = md; redv[w][1] = mxy; redv[w][2] = mth;
  }
  __syncthreads();
  if (tid == 0) {
    float a0 = fmaxf(fmaxf(redv[0][0], redv[1][0]), fmaxf(redv[2][0], redv[3][0]));
    float a1 = fmaxf(fmaxf(redv[0][1], redv[1][1]), fmaxf(redv[2][1], redv[3][1]));
    float a2 = fmaxf(fmaxf(redv[0][2], redv[1][2]), fmaxf(redv[2][2], redv[3][2]));
    part[(size_t)blockIdx.x * 3 + 0] = a0;
    part[(size_t)blockIdx.x * 3 + 1] = a1;
    part[(size_t)blockIdx.x * 3 + 2] = a2;
  }
}

// ---------- pass C: maxima reduce + recompute metrics + cost + top-4 --------
// one block (1024 threads = 16 waves) per (b,m); thread t owns n = 4t..4t+3.
// Last block of EACH BATCH (done[b] counter) finalizes that batch's outputs:
// 8 finalizers on 8 CUs, vectorized (one uint4/ulonglong2 iteration each).
__global__ __launch_bounds__(1024) void k_assign(
    const float* __restrict__ sadA, const float4* __restrict__ pc4,
    const float* __restrict__ cls, const float* __restrict__ tgts,
    const int* __restrict__ imgw_p, const float* __restrict__ part,
    const void* __restrict__ masks, const int* __restrict__ flag,
    unsigned* __restrict__ mmask, unsigned long long* __restrict__ cmin,
    int* __restrict__ done, int* __restrict__ out) {
  const int b = blockIdx.x >> 5;
  const int m = blockIdx.x & 31;
  const bool act = getmask(masks, *flag, b * MM + m);   // block-uniform

  const int tid = threadIdx.x;
  __shared__ float bcast[3];
  __shared__ float scal[8];   // 0:cx 1:cy 2:th 3:len 4:v30
  __shared__ float ls_c[64];  __shared__ int ls_ci[64];
  __shared__ float ls_v[64];  __shared__ int ls_vi[64];
  __shared__ int lastflag;

  if (act) {
    // reduce part[b*64 .. +63][3] -> batch maxima (one wave per metric)
    if (tid < 192) {
      int g = tid >> 6, e = tid & 63;
      float v = part[((size_t)(b * 64 + e)) * 3 + g];
      for (int off = 32; off; off >>= 1) v = fmaxf(v, __shfl_down(v, off));
      if ((tid & 63) == 0) bcast[g] = v;
    }
    // wave 14: valid-count V for target row m (same predicate as k_pairs)
    if (tid >= 896 && tid < 960) {
      int lane = tid - 896;
      const float* trow = tgts + ((size_t)(b * MM + m)) * DD;
      const float imgw = (float)(*imgw_p);
      float t0 = trow[6 + lane];
      int c = (t0 >= 0.0f && t0 < imgw) ? 1 : 0;
      if (lane < KK - 64) {
        float t1 = trow[6 + 64 + lane];
        c += (t1 >= 0.0f && t1 < imgw) ? 1 : 0;
      }
      for (int off = 32; off; off >>= 1) c += __shfl_down(c, off);
      if (lane == 0) {
        float V = (float)c;
        scal[3] = (V > 0.f) ? V : 1.0f;
        scal[4] = 30.0f * V;
      }
    }
    if (tid == 1023) {
      const float* trow = tgts + ((size_t)(b * MM + m)) * DD;
      scal[0] = trow[2]; scal[1] = trow[3]; scal[2] = trow[4];
    }
    __syncthreads();

    const float maxd = fmaxf(bcast[0], 1e-6f);
    const float maxxy = fmaxf(bcast[1], 1e-6f);
    const float maxth = fmaxf(bcast[2], 1e-6f);
    const float tcx = scal[0], tcy = scal[1], tth = scal[2];
    const float len = scal[3], v30 = scal[4];
    const int label = (int)tgts[((size_t)b * MM + m) * DD + 1];

    const int n0 = tid << 2;
    float4 s4 = *reinterpret_cast<const float4*>(sadA + ((size_t)(b * MM + m)) * NN + n0);
    const float4* pcb = pc4 + (size_t)b * NN + n0;
    float4 q0 = pcb[0], q1 = pcb[1], q2 = pcb[2], q3 = pcb[3];
    const float4* cbase = reinterpret_cast<const float4*>(cls + ((size_t)b * NN + n0) * 2);
    float4 c0 = cbase[0], c1 = cbase[1];

    float se[4] = {s4.x, s4.y, s4.z, s4.w};
    float cxe[4] = {q0.x, q1.x, q2.x, q3.x};
    float cye[4] = {q0.y, q1.y, q2.y, q3.y};
    float the[4] = {q0.z, q1.z, q2.z, q3.z};
    float clv[4] = {label ? c0.y : c0.x, label ? c0.w : c0.z,
                    label ? c1.y : c1.x, label ? c1.w : c1.z};

    float cc[4]; int ci[4]; float vv[4];
#pragma unroll
    for (int e = 0; e < 4; ++e) {
      float sad = se[e];
      float dval = sad / len;                       // == k_pairs dval bitwise
      float dx = cxe[e] - tcx, dy = cye[e] - tcy;
      float xyv = sqrtf(fmaf(dx, dx, dy * dy));     // == k_pairs xyv bitwise
      float thv = fabsf(the[e] - tth);
      float iv = (v30 - sad) / ((v30 + sad) + 1e-9f);
      float ds = (1.0f - dval / maxd) + 0.01f;
      float xs = (1.0f - xyv / maxxy) + 0.01f;
      float ts = (1.0f - thv / maxth) + 0.01f;
      float r = (ds * xs) * ts;
      cc[e] = -(r * r) * 3.0f + clv[e] * 1.0f;
      ci[e] = n0 + e;
      vv[e] = fmaxf(iv, 0.0f);
    }

    const int wid = tid >> 6, lane = tid & 63;
    unsigned usedC = 0, usedV = 0;
    float wcv[4]; int wci[4]; float wvv[4]; int wvi[4];

#pragma unroll
    for (int r = 0; r < 4; ++r) {
      // ---- cost: extract wave min by (c asc, idx asc) ----
      float bv = 3e38f; int bi = 0x7fffffff; int be = -1;
#pragma unroll
      for (int e = 0; e < 4; ++e)
        if (!((usedC >> e) & 1) && (cc[e] < bv || (cc[e] == bv && ci[e] < bi))) {
          bv = cc[e]; bi = ci[e]; be = e;
        }
      float v = bv; int i = bi;
#pragma unroll
      for (int off = 32; off; off >>= 1) {
        float ov = __shfl_xor(v, off); int oi = __shfl_xor(i, off);
        if (ov < v || (ov == v && oi < i)) { v = ov; i = oi; }
      }
      if (be >= 0 && i == bi) usedC |= 1u << be;   // unique n -> unique winner
      wcv[r] = v; wci[r] = i;

      // ---- iou: extract wave max by (v desc, idx asc) ----
      float bw = -1.0f; int bj = 0x7fffffff; int bf = -1;
#pragma unroll
      for (int e = 0; e < 4; ++e)
        if (!((usedV >> e) & 1) && (vv[e] > bw || (vv[e] == bw && ci[e] < bj))) {
          bw = vv[e]; bj = ci[e]; bf = e;
        }
      float w = bw; int j = bj;
#pragma unroll
      for (int off = 32; off; off >>= 1) {
        float ow = __shfl_xor(w, off); int oj = __shfl_xor(j, off);
        if (ow > w || (ow == w && oj < j)) { w = ow; j = oj; }
      }
      if (bf >= 0 && j == bj) usedV |= 1u << bf;
      wvv[r] = w; wvi[r] = j;
    }

    if (lane == 0) {
#pragma unroll
      for (int r = 0; r < 4; ++r) {
        ls_c[wid * 4 + r] = wcv[r]; ls_ci[wid * 4 + r] = wci[r];
        ls_v[wid * 4 + r] = wvv[r]; ls_vi[wid * 4 + r] = wvi[r];
      }
    }
    __syncthreads();

    if (tid < 64) {
      float c = ls_c[tid]; int i = ls_ci[tid];
      float w = ls_v[tid]; int j = ls_vi[tid];
      int gidx[4]; float gcst[4]; float gsum = 0.0f;
#pragma unroll
      for (int r = 0; r < 4; ++r) {
        float v = c; int vi = i;
#pragma unroll
        for (int off = 32; off; off >>= 1) {
          float ov = __shfl_xor(v, off); int oi = __shfl_xor(vi, off);
          if (ov < v || (ov == v && oi < vi)) { v = ov; vi = oi; }
        }
        if (i == vi) c = 3e38f;                    // consume winner
        gidx[r] = vi; gcst[r] = v;

        float u = w; int ui = j;
#pragma unroll
        for (int off = 32; off; off >>= 1) {
          float ou = __shfl_xor(u, off); int oi = __shfl_xor(ui, off);
          if (ou > u || (ou == u && oi < ui)) { u = ou; ui = oi; }
        }
        if (j == ui) w = -1.0f;
        gsum += u;
      }
      if (tid == 0) {
        int k = (int)gsum;                         // trunc == floor (gsum >= 0)
        if (k < 1) k = 1;
        if (k > 4) k = 4;
        for (int s = 0; s < k; ++s) {
          atomicOr(&mmask[(size_t)b * NN + gidx[s]], 1u << m);
          atomicMin(&cmin[(size_t)b * NN + gidx[s]], packkey(gcst[s], m));
        }
      }
    }
  }

  // ---- per-batch last-block finalize (no spin; completion-ordered) ----
  __syncthreads();
  if (tid == 0) {
    __threadfence();                     // release this block's atomics
    int prev = atomicAdd(&done[b], 1);
    lastflag = (prev == MM - 1) ? 1 : 0;
  }
  __syncthreads();
  if (lastflag) {
    __threadfence();                     // acquire all batch-b blocks' atomics
    const int base = b * NN + (tid << 2);            // 1024 thr x 4 = 4096 = NN
    uint4 mm4 = *reinterpret_cast<const uint4*>(mmask + base);
    ulonglong2 c01 = *reinterpret_cast<const ulonglong2*>(cmin + base);
    ulonglong2 c23 = *reinterpret_cast<const ulonglong2*>(cmin + base + 2);
    int4 a4, t4o;
    a4.x = mm4.x ? 1 : 0;  t4o.x = mm4.x ? (int)(unsigned)(c01.x & 0xFFFFFFFFull) : -1;
    a4.y = mm4.y ? 1 : 0;  t4o.y = mm4.y ? (int)(unsigned)(c01.y & 0xFFFFFFFFull) : -1;
    a4.z = mm4.z ? 1 : 0;  t4o.z = mm4.z ? (int)(unsigned)(c23.x & 0xFFFFFFFFull) : -1;
    a4.w = mm4.w ? 1 : 0;  t4o.w = mm4.w ? (int)(unsigned)(c23.y & 0xFFFFFFFFull) : -1;
    *reinterpret_cast<int4*>(out + base) = a4;
    *reinterpret_cast<int4*>(out + BB * NN + base) = t4o;
  }
}

extern "C" void kernel_launch(void* const* d_in, const int* in_sizes, int n_in,
                              void* d_out, int out_size, void* d_ws, size_t ws_size,
                              hipStream_t stream) {
  const float* preds = (const float*)d_in[0];
  const float* tgts = (const float*)d_in[1];
  const void* masks = d_in[2];
  const int* imgw = (const int*)d_in[3];

  char* ws = (char*)d_ws;
  float* sadA = (float*)ws;                                   // B*M*N*4 = 4 MiB
  char* p = ws + (size_t)BB * MM * NN * sizeof(float);
  float4* pc4 = (float4*)p;                                   // B*N*16 = 512 KB
  p += (size_t)BB * NN * sizeof(float4);
  float* cls = (float*)p;                                     // B*N*2 floats
  p += (size_t)BB * NN * 2 * sizeof(float);
  float* part = (float*)p;                                    // 512*3 floats
  p += (size_t)1024 * 3 * sizeof(float);
  unsigned* mmask = (unsigned*)p;                             // B*N (16B-aligned)
  p += (size_t)BB * NN * sizeof(unsigned);
  unsigned long long* cmin = (unsigned long long*)p;          // B*N * 8B (16B-aligned)
  p += (size_t)BB * NN * sizeof(unsigned long long);
  int* flag = (int*)p;
  int* done = (int*)(p + 64);                                 // int[BB]

  k_pairs<<<dim3(BB * 64), dim3(256), 0, stream>>>(
      preds, tgts, imgw, (const unsigned char*)masks,
      sadA, pc4, cls, part, mmask, cmin, flag, done);
  k_assign<<<dim3(BB * MM), dim3(1024), 0, stream>>>(
      sadA, pc4, cls, tgts, imgw, part, masks, flag, mmask, cmin,
      done, (int*)d_out);
}

// Round 15
// 40.770 us; speedup vs baseline: 5.1631x; 1.2209x over previous
//
#include <hip/hip_runtime.h>
#include <stdint.h>

#define BB 8
#define NN 4096
#define MM 32
#define KK 72
#define DD 78
#define PAD 76            // LDS row stride (floats): 76*4=304 B, 16B-aligned

static constexpr float EPSF = 1e-12f;

__device__ inline bool getmask(const void* masks, int flag, int i) {
  if (flag) return ((const unsigned char*)masks)[i] != 0;
  return ((const int*)masks)[i] != 0;
}

// orderable key: min over (cost asc, m asc) == reference argmin-first semantics
__device__ inline unsigned long long packkey(float c, int m) {
  unsigned u = __float_as_uint(c);
  unsigned k = ((int)u < 0) ? ~u : (u ^ 0x80000000u);
  return ((unsigned long long)k << 32) | (unsigned)m;
}

// ---------- pass A: 512 blocks = 8 b x 64 chunks(64 n); 256 thr = 16 mt x 16 nt
// each thread computes a 2m x 4n tile (8 pairs). Validity mask recomputed in
// VALU (depends only on t) -> no am_s in LDS: 6 b128 reads per q for 8 quads.
__global__ __launch_bounds__(256) void k_pairs(
    const float* __restrict__ preds, const float* __restrict__ tgts,
    const int* __restrict__ imgw_p, const unsigned char* __restrict__ masks_raw,
    float* __restrict__ sadA, float4* __restrict__ pc4, float* __restrict__ cls,
    float* __restrict__ part, unsigned* __restrict__ mmask,
    unsigned long long* __restrict__ cmin, int* __restrict__ flag) {
  __shared__ __align__(16) float t_xs[MM][PAD];
  __shared__ __align__(16) float px_s[64][PAD];
  __shared__ float pc_s[64][4];                   // cx, cy, th
  __shared__ float t_cx[MM], t_cy[MM], t_th[MM], t_len[MM];
  __shared__ float redv[4][3];

  const int b = blockIdx.x >> 6;
  const int n0 = (blockIdx.x & 63) << 6;          // 64 n per block
  const int tid = threadIdx.x;
  const float imgw = (float)(*imgw_p);

  // zero this block's mmask/cmin slice (512 blocks x 64 = B*N)
  if (tid < 64) {
    mmask[blockIdx.x * 64 + tid] = 0u;
    cmin[blockIdx.x * 64 + tid] = ~0ull;
  }
  // mask dtype detect: int32 masks have zero bytes at i%4!=0
  if (blockIdx.x == 0 && tid < 64) {
    int i = tid * 4;
    bool nz = false;
#pragma unroll
    for (int j = 1; j < 4; ++j)
      if (masks_raw[i + j] != 0) nz = true;
    unsigned long long bal = __ballot(nz);
    if (tid == 0) *flag = (bal != 0ull) ? 1 : 0;
  }

  // stage targets
  for (int idx = tid; idx < MM * DD; idx += 256) {
    int m = idx / DD, j = idx - m * DD;
    float v = tgts[((size_t)b * MM + m) * DD + j];
    if (j >= 6) t_xs[m][j - 6] = v;
    else if (j == 2) t_cx[m] = v;
    else if (j == 3) t_cy[m] = v;
    else if (j == 4) t_th[m] = v;
  }
  // stage the 64 pred x-rows
  for (int idx = tid; idx < 64 * KK; idx += 256) {
    int ni = idx / KK, k = idx - ni * KK;
    px_s[ni][k] = preds[((size_t)b * NN + (n0 + ni)) * DD + 6 + k];
  }
  // stage pred cx,cy,th
  if (tid < 192) {
    int ni = tid / 3, c = tid - ni * 3;
    pc_s[ni][c] = preds[((size_t)b * NN + (n0 + ni)) * DD + 2 + c];
  }
  // focal-cost class diffs (64 rows x 2 labels)
  if (tid < 128) {
    int ni = tid >> 1, c = tid & 1;
    float lg = preds[((size_t)b * NN + (n0 + ni)) * DD + c];
    float pp = 1.0f / (1.0f + expf(-lg));
    float neg = -logf(1.0f - pp + EPSF) * 0.75f * (pp * pp);
    float pos = -logf(pp + EPSF) * 0.25f * ((1.0f - pp) * (1.0f - pp));
    cls[((size_t)b * NN + (n0 + ni)) * 2 + c] = pos - neg;
  }
  __syncthreads();
  // export compact (cx,cy,th) table for k_assign
  if (tid < 64)
    pc4[(size_t)b * NN + n0 + tid] =
        make_float4(pc_s[tid][0], pc_s[tid][1], pc_s[tid][2], 0.0f);
  // valid-count per target row (same predicate as the inner mask; exact <=72)
  if (tid < MM) {
    int V = 0;
    for (int k = 0; k < KK; ++k) {
      float t = t_xs[tid][k];
      if (t >= 0.0f && t < imgw) V++;
    }
    t_len[tid] = (float)(V > 0 ? V : 1);
  }
  __syncthreads();

  const int mt = tid >> 4;       // 0..15 -> m = 2mt, 2mt+1
  const int nt = tid & 15;       // 0..15 -> n = n0 + nt + 16j, j=0..3
  const int mbase = mt << 1;

  const float4* t0r = reinterpret_cast<const float4*>(&t_xs[mbase + 0][0]);
  const float4* t1r = reinterpret_cast<const float4*>(&t_xs[mbase + 1][0]);
  const float4* p0r = reinterpret_cast<const float4*>(&px_s[nt][0]);
  const float4* p1r = reinterpret_cast<const float4*>(&px_s[nt + 16][0]);
  const float4* p2r = reinterpret_cast<const float4*>(&px_s[nt + 32][0]);
  const float4* p3r = reinterpret_cast<const float4*>(&px_s[nt + 48][0]);

  float s00 = 0.f, s01 = 0.f, s02 = 0.f, s03 = 0.f;
  float s10 = 0.f, s11 = 0.f, s12 = 0.f, s13 = 0.f;

#define MSK(T) \
  make_float4(((T).x >= 0.0f && (T).x < imgw) ? 1.0f : 0.0f, \
              ((T).y >= 0.0f && (T).y < imgw) ? 1.0f : 0.0f, \
              ((T).z >= 0.0f && (T).z < imgw) ? 1.0f : 0.0f, \
              ((T).w >= 0.0f && (T).w < imgw) ? 1.0f : 0.0f)
#define ST(S, T, A, P)                       \
  S = fmaf(fabsf((T).x - (P).x), (A).x, S);  \
  S = fmaf(fabsf((T).y - (P).y), (A).y, S);  \
  S = fmaf(fabsf((T).z - (P).z), (A).z, S);  \
  S = fmaf(fabsf((T).w - (P).w), (A).w, S);
#pragma unroll 6
  for (int q = 0; q < KK / 4; ++q) {
    float4 T0 = t0r[q], T1 = t1r[q];
    float4 A0 = MSK(T0), A1 = MSK(T1);      // mask from t only; reused over 4 n
    float4 P0 = p0r[q], P1 = p1r[q], P2 = p2r[q], P3 = p3r[q];
    ST(s00, T0, A0, P0) ST(s01, T0, A0, P1) ST(s02, T0, A0, P2) ST(s03, T0, A0, P3)
    ST(s10, T1, A1, P0) ST(s11, T1, A1, P1) ST(s12, T1, A1, P2) ST(s13, T1, A1, P3)
  }
#undef ST
#undef MSK

  float md = 0.f, mxy = 0.f, mth = 0.f;
#define FIN(S, MI, NJ)                                                        \
  {                                                                           \
    float sad = S;                                                            \
    int mi = mbase + (MI);                                                    \
    int nr = nt + 16 * (NJ);                                                  \
    float dval = sad / t_len[mi];            /* IEEE div: == k_assign */      \
    float dx = pc_s[nr][0] - t_cx[mi], dy = pc_s[nr][1] - t_cy[mi];           \
    float xyv = sqrtf(fmaf(dx, dx, dy * dy)); /* explicit fma: == k_assign */ \
    float thv = fabsf(pc_s[nr][2] - t_th[mi]);                                \
    sadA[((size_t)(b * MM + mi)) * NN + n0 + nr] = sad;                       \
    md = fmaxf(md, dval); mxy = fmaxf(mxy, xyv); mth = fmaxf(mth, thv);       \
  }
  FIN(s00, 0, 0) FIN(s01, 0, 1) FIN(s02, 0, 2) FIN(s03, 0, 3)
  FIN(s10, 1, 0) FIN(s11, 1, 1) FIN(s12, 1, 2) FIN(s13, 1, 3)
#undef FIN

  // block max -> plain store to part[block][3] (NO atomics: round-5 lesson)
  for (int off = 32; off; off >>= 1) {
    md = fmaxf(md, __shfl_down(md, off));
    mxy = fmaxf(mxy, __shfl_down(mxy, off));
    mth = fmaxf(mth, __shfl_down(mth, off));
  }
  if ((tid & 63) == 0) {
    int w = tid >> 6;
    redv[w][0] = md; redv[w][1] = mxy; redv[w][2] = mth;
  }
  __syncthreads();
  if (tid == 0) {
    float a0 = fmaxf(fmaxf(redv[0][0], redv[1][0]), fmaxf(redv[2][0], redv[3][0]));
    float a1 = fmaxf(fmaxf(redv[0][1], redv[1][1]), fmaxf(redv[2][1], redv[3][1]));
    float a2 = fmaxf(fmaxf(redv[0][2], redv[1][2]), fmaxf(redv[2][2], redv[3][2]));
    part[(size_t)blockIdx.x * 3 + 0] = a0;
    part[(size_t)blockIdx.x * 3 + 1] = a1;
    part[(size_t)blockIdx.x * 3 + 2] = a2;
  }
}

// ---------- pass C: maxima reduce + recompute metrics + cost + top-4 --------
// one block (1024 threads = 16 waves) per (b,m); thread t owns n = 4t..4t+3
__global__ __launch_bounds__(1024) void k_assign(
    const float* __restrict__ sadA, const float4* __restrict__ pc4,
    const float* __restrict__ cls, const float* __restrict__ tgts,
    const int* __restrict__ imgw_p, const float* __restrict__ part,
    const void* __restrict__ masks, const int* __restrict__ flag,
    unsigned* __restrict__ mmask, unsigned long long* __restrict__ cmin) {
  const int b = blockIdx.x >> 5;
  const int m = blockIdx.x & 31;
  if (!getmask(masks, *flag, b * MM + m)) return;   // block-uniform exit

  const int tid = threadIdx.x;
  __shared__ float bcast[3];
  __shared__ float scal[8];   // 0:cx 1:cy 2:th 3:len 4:v30

  // reduce part[b*64 .. +63][3] -> batch maxima (one wave per metric)
  if (tid < 192) {
    int g = tid >> 6, e = tid & 63;
    float v = part[((size_t)(b * 64 + e)) * 3 + g];
    for (int off = 32; off; off >>= 1) v = fmaxf(v, __shfl_down(v, off));
    if ((tid & 63) == 0) bcast[g] = v;
  }
  // wave 14: valid-count V for target row m (same predicate as k_pairs)
  if (tid >= 896 && tid < 960) {
    int lane = tid - 896;
    const float* trow = tgts + ((size_t)(b * MM + m)) * DD;
    const float imgw = (float)(*imgw_p);
    float t0 = trow[6 + lane];
    int c = (t0 >= 0.0f && t0 < imgw) ? 1 : 0;
    if (lane < KK - 64) {
      float t1 = trow[6 + 64 + lane];
      c += (t1 >= 0.0f && t1 < imgw) ? 1 : 0;
    }
    for (int off = 32; off; off >>= 1) c += __shfl_down(c, off);
    if (lane == 0) {
      float V = (float)c;
      scal[3] = (V > 0.f) ? V : 1.0f;
      scal[4] = 30.0f * V;
    }
  }
  if (tid == 1023) {
    const float* trow = tgts + ((size_t)(b * MM + m)) * DD;
    scal[0] = trow[2]; scal[1] = trow[3]; scal[2] = trow[4];
  }
  __syncthreads();

  const float maxd = fmaxf(bcast[0], 1e-6f);
  const float maxxy = fmaxf(bcast[1], 1e-6f);
  const float maxth = fmaxf(bcast[2], 1e-6f);
  const float tcx = scal[0], tcy = scal[1], tth = scal[2];
  const float len = scal[3], v30 = scal[4];
  const int label = (int)tgts[((size_t)b * MM + m) * DD + 1];

  const int n0 = tid << 2;
  float4 s4 = *reinterpret_cast<const float4*>(sadA + ((size_t)(b * MM + m)) * NN + n0);
  const float4* pcb = pc4 + (size_t)b * NN + n0;
  float4 q0 = pcb[0], q1 = pcb[1], q2 = pcb[2], q3 = pcb[3];
  const float4* cbase = reinterpret_cast<const float4*>(cls + ((size_t)b * NN + n0) * 2);
  float4 c0 = cbase[0], c1 = cbase[1];

  float se[4] = {s4.x, s4.y, s4.z, s4.w};
  float cxe[4] = {q0.x, q1.x, q2.x, q3.x};
  float cye[4] = {q0.y, q1.y, q2.y, q3.y};
  float the[4] = {q0.z, q1.z, q2.z, q3.z};
  float clv[4] = {label ? c0.y : c0.x, label ? c0.w : c0.z,
                  label ? c1.y : c1.x, label ? c1.w : c1.z};

  float cc[4]; int ci[4]; float vv[4];
#pragma unroll
  for (int e = 0; e < 4; ++e) {
    float sad = se[e];
    float dval = sad / len;                       // == k_pairs dval bitwise
    float dx = cxe[e] - tcx, dy = cye[e] - tcy;
    float xyv = sqrtf(fmaf(dx, dx, dy * dy));     // == k_pairs xyv bitwise
    float thv = fabsf(the[e] - tth);
    float iv = (v30 - sad) / ((v30 + sad) + 1e-9f);
    float ds = (1.0f - dval / maxd) + 0.01f;
    float xs = (1.0f - xyv / maxxy) + 0.01f;
    float ts = (1.0f - thv / maxth) + 0.01f;
    float r = (ds * xs) * ts;
    cc[e] = -(r * r) * 3.0f + clv[e] * 1.0f;
    ci[e] = n0 + e;
    vv[e] = fmaxf(iv, 0.0f);
  }

  __shared__ float ls_c[64];  __shared__ int ls_ci[64];
  __shared__ float ls_v[64];  __shared__ int ls_vi[64];

  const int wid = tid >> 6, lane = tid & 63;
  unsigned usedC = 0, usedV = 0;
  float wcv[4]; int wci[4]; float wvv[4]; int wvi[4];

#pragma unroll
  for (int r = 0; r < 4; ++r) {
    // ---- cost: extract wave min by (c asc, idx asc) ----
    float bv = 3e38f; int bi = 0x7fffffff; int be = -1;
#pragma unroll
    for (int e = 0; e < 4; ++e)
      if (!((usedC >> e) & 1) && (cc[e] < bv || (cc[e] == bv && ci[e] < bi))) {
        bv = cc[e]; bi = ci[e]; be = e;
      }
    float v = bv; int i = bi;
#pragma unroll
    for (int off = 32; off; off >>= 1) {
      float ov = __shfl_xor(v, off); int oi = __shfl_xor(i, off);
      if (ov < v || (ov == v && oi < i)) { v = ov; i = oi; }
    }
    if (be >= 0 && i == bi) usedC |= 1u << be;   // unique n -> unique winner
    wcv[r] = v; wci[r] = i;

    // ---- iou: extract wave max by (v desc, idx asc) ----
    float bw = -1.0f; int bj = 0x7fffffff; int bf = -1;
#pragma unroll
    for (int e = 0; e < 4; ++e)
      if (!((usedV >> e) & 1) && (vv[e] > bw || (vv[e] == bw && ci[e] < bj))) {
        bw = vv[e]; bj = ci[e]; bf = e;
      }
    float w = bw; int j = bj;
#pragma unroll
    for (int off = 32; off; off >>= 1) {
      float ow = __shfl_xor(w, off); int oj = __shfl_xor(j, off);
      if (ow > w || (ow == w && oj < j)) { w = ow; j = oj; }
    }
    if (bf >= 0 && j == bj) usedV |= 1u << bf;
    wvv[r] = w; wvi[r] = j;
  }

  if (lane == 0) {
#pragma unroll
    for (int r = 0; r < 4; ++r) {
      ls_c[wid * 4 + r] = wcv[r]; ls_ci[wid * 4 + r] = wci[r];
      ls_v[wid * 4 + r] = wvv[r]; ls_vi[wid * 4 + r] = wvi[r];
    }
  }
  __syncthreads();

  if (tid < 64) {
    float c = ls_c[tid]; int i = ls_ci[tid];
    float w = ls_v[tid]; int j = ls_vi[tid];
    int gidx[4]; float gcst[4]; float gsum = 0.0f;
#pragma unroll
    for (int r = 0; r < 4; ++r) {
      float v = c; int vi = i;
#pragma unroll
      for (int off = 32; off; off >>= 1) {
        float ov = __shfl_xor(v, off); int oi = __shfl_xor(vi, off);
        if (ov < v || (ov == v && oi < vi)) { v = ov; vi = oi; }
      }
      if (i == vi) c = 3e38f;                    // consume winner
      gidx[r] = vi; gcst[r] = v;

      float u = w; int ui = j;
#pragma unroll
      for (int off = 32; off; off >>= 1) {
        float ou = __shfl_xor(u, off); int oi = __shfl_xor(ui, off);
        if (ou > u || (ou == u && oi < ui)) { u = ou; ui = oi; }
      }
      if (j == ui) w = -1.0f;
      gsum += u;
    }
    if (tid == 0) {
      int k = (int)gsum;                         // trunc == floor (gsum >= 0)
      if (k < 1) k = 1;
      if (k > 4) k = 4;
      for (int s = 0; s < k; ++s) {
        atomicOr(&mmask[(size_t)b * NN + gidx[s]], 1u << m);
        atomicMin(&cmin[(size_t)b * NN + gidx[s]], packkey(gcst[s], m));
      }
    }
  }
}

// ---------- pass D: trivial finalize ----------------------------------------
__global__ __launch_bounds__(256) void k_final(
    const unsigned* __restrict__ mmask,
    const unsigned long long* __restrict__ cmin, int* __restrict__ out) {
  int idx = blockIdx.x * 256 + threadIdx.x;   // over B*N
  if (idx >= BB * NN) return;
  unsigned mm = mmask[idx];
  int pc = __popc(mm);
  int t = pc ? (int)(unsigned)(cmin[idx] & 0xFFFFFFFFull) : -1;
  out[idx] = pc ? 1 : 0;
  out[BB * NN + idx] = t;
}

extern "C" void kernel_launch(void* const* d_in, const int* in_sizes, int n_in,
                              void* d_out, int out_size, void* d_ws, size_t ws_size,
                              hipStream_t stream) {
  const float* preds = (const float*)d_in[0];
  const float* tgts = (const float*)d_in[1];
  const void* masks = d_in[2];
  const int* imgw = (const int*)d_in[3];

  char* ws = (char*)d_ws;
  float* sadA = (float*)ws;                                   // B*M*N*4 = 4 MiB
  char* p = ws + (size_t)BB * MM * NN * sizeof(float);
  float4* pc4 = (float4*)p;                                   // B*N*16 = 512 KB
  p += (size_t)BB * NN * sizeof(float4);
  float* cls = (float*)p;                                     // B*N*2 floats
  p += (size_t)BB * NN * 2 * sizeof(float);
  float* part = (float*)p;                                    // 512*3 floats
  p += (size_t)1024 * 3 * sizeof(float);
  unsigned* mmask = (unsigned*)p;                             // B*N
  p += (size_t)BB * NN * sizeof(unsigned);
  unsigned long long* cmin = (unsigned long long*)p;          // B*N * 8B
  p += (size_t)BB * NN * sizeof(unsigned long long);
  int* flag = (int*)p;

  k_pairs<<<dim3(BB * 64), dim3(256), 0, stream>>>(
      preds, tgts, imgw, (const unsigned char*)masks,
      sadA, pc4, cls, part, mmask, cmin, flag);
  k_assign<<<dim3(BB * MM), dim3(1024), 0, stream>>>(
      sadA, pc4, cls, tgts, imgw, part, masks, flag, mmask, cmin);
  k_final<<<dim3((BB * NN + 255) / 256), dim3(256), 0, stream>>>(
      mmask, cmin, (int*)d_out);
}